// Round 2
// baseline (436.809 us; speedup 1.0000x reference)
//
#include <hip/hip_runtime.h>
#include <math.h>

#define M   24
#define TS  60
#define NX  192
#define NY  192
#define H_  4
#define D_  8
#define NTS 50   // N_TIME_STEPS
#define NG  50

// Setup results computed by prep each call (always fully rewritten —
// no cross-call state dependence).
__device__ float g_w[M];
__device__ int   g_ti[NTS][M];
__device__ int   g_ix[NG];
__device__ float g_fx[NG];
__device__ float g_mx[NG];
__device__ int   g_iy[M][NG];
__device__ float g_fy[M][NG];
__device__ float g_my[M][NG];

// Block 0: full prep (weights, ti, interp setups).
// Blocks >= 1: zero-init d_out and write the boundary-target columns.
__global__ __launch_bounds__(256) void prep_init_kernel(
    const float* __restrict__ params, const float* __restrict__ src_y,
    const float* __restrict__ stl,
    const float* __restrict__ Wq, const float* __restrict__ bq,
    const float* __restrict__ Wk, const float* __restrict__ bk,
    const float* __restrict__ lyt_p, const float* __restrict__ ccu_p,
    const float* __restrict__ cni_p,
    float* __restrict__ out)
{
    const int tid = threadIdx.x;

    if (blockIdx.x > 0) {
        // ---- output init: zeros except boundary target columns ----
        const int idx = (blockIdx.x - 1) * blockDim.x + tid;
        const int total = 2 * NTS * NG * NG;
        if (idx < total) {
            const int j = idx % NG;
            const int f = idx / (NTS * NG * NG);
            float v = 0.0f;
            if (f == 0 && j == 0)    v = ccu_p[0];
            if (f == 1 && j == NG-1) v = cni_p[0];
            out[idx] = v;
        }
        return;
    }

    __shared__ float s_logits[M][H_];
    __shared__ float s_sw[M];

    const float ly_target = lyt_p[0];
    const float c_cu_t = ccu_p[0];
    const float c_ni_t = cni_p[0];

    const float t_ly = (ly_target - 30.0f) / 90.0f;
    const float t_cu = c_cu_t / 0.0029f;
    const float t_ni = c_ni_t / 0.0018f;

    // ---- per-m logits + similarity weight ----
    if (tid < M) {
        const int m = tid;
        const float ly  = params[m*3 + 0];
        const float ccu = params[m*3 + 1];
        const float cni = params[m*3 + 2];
        const float ly_n = (ly - 30.0f) / 90.0f;
        const float cu_n = ccu / 0.0029f;
        const float ni_n = cni / 0.0018f;
        for (int h = 0; h < H_; ++h) {
            float acc = 0.0f;
            for (int d = 0; d < D_; ++d) {
                const int col = h*D_ + d;
                const float q = t_ly*Wq[0*32+col] + t_cu*Wq[1*32+col] + t_ni*Wq[2*32+col] + bq[col];
                const float k = ly_n*Wk[0*32+col] + cu_n*Wk[1*32+col] + ni_n*Wk[2*32+col] + bk[col];
                acc += k * q;
            }
            s_logits[m][h] = acc / sqrtf(8.0f);
        }
        const float dly = ly_n - t_ly, dcu = cu_n - t_cu, dni = ni_n - t_ni;
        const float d2 = (dly*dly + dcu*dcu + dni*dni) / 0.04f;
        s_sw[m] = expf(-d2 * 0.5f);
    }
    __syncthreads();

    if (tid == 0) {
        float attn[M];
        for (int m = 0; m < M; ++m) attn[m] = 0.0f;
        for (int h = 0; h < H_; ++h) {
            float mxv = -1e30f;
            for (int m = 0; m < M; ++m) mxv = fmaxf(mxv, s_logits[m][h]);
            float e[M]; float s = 0.0f;
            for (int m = 0; m < M; ++m) { e[m] = expf(s_logits[m][h] - mxv); s += e[m]; }
            for (int m = 0; m < M; ++m) attn[m] += e[m] / s;
        }
        float ssw = 0.0f;
        for (int m = 0; m < M; ++m) ssw += s_sw[m];
        float w[M]; float wsum = 0.0f;
        for (int m = 0; m < M; ++m) {
            w[m] = (attn[m] * 0.25f) * (s_sw[m] / (ssw + 1e-12f));
            wsum += w[m];
        }
        for (int m = 0; m < M; ++m) g_w[m] = w[m] / (wsum + 1e-12f);
    }

    // ---- ti[t][m] : banker's rounding to match jnp.round ----
    const float step_t = 200.0f / 49.0f;
    for (int idx = tid; idx < NTS*M; idx += blockDim.x) {
        const int t = idx / M, m = idx % M;
        const float tt = (t == NTS-1) ? 200.0f : step_t * (float)t;
        const float r = tt / stl[m] * 59.0f;
        int ti = (int)rintf(r);
        ti = ti < 0 ? 0 : (ti > TS-1 ? TS-1 : ti);
        g_ti[t][m] = ti;
    }

    // ---- x-axis interp setup (grid = linspace(0,100,192), q = linspace(0,100,50)) ----
    if (tid < NG) {
        const int i = tid;
        const float step_x = 100.0f / 191.0f;
        const float step_q = 100.0f / 49.0f;
        const float q = (i == NG-1) ? 100.0f : step_q * (float)i;
        int pos = 0;  // searchsorted(grid, q, 'right')
        for (int g = 0; g < NX; ++g) {
            const float gv = (g == NX-1) ? 100.0f : step_x * (float)g;
            if (gv <= q) pos = g + 1;
        }
        int id = pos - 1;
        id = id < 0 ? 0 : (id > NX-2 ? NX-2 : id);
        const float g0 = (id   == NX-1) ? 100.0f : step_x * (float)id;
        const float g1 = (id+1 == NX-1) ? 100.0f : step_x * (float)(id+1);
        g_ix[i] = id;
        g_fx[i] = (q - g0) / (g1 - g0);
        g_mx[i] = (q >= 0.0f && q <= 100.0f) ? 1.0f : 0.0f;
    }

    // ---- y-axis interp setup per m (grid = src_y[m,:] * (ly_target/lys[m])) ----
    for (int idx = tid; idx < M*NG; idx += blockDim.x) {
        const int m = idx / NG, j = idx % NG;
        const float scale = ly_target / params[m*3 + 0];   // IEEE fp32 div, matches ref
        const float q = (float)j / 49.0f * ly_target;
        const float* sy = src_y + m*NY;
        int pos = 0;
        for (int g = 0; g < NY; ++g) {
            const float gv = sy[g] * scale;                // IEEE fp32 mul, matches ref
            if (gv <= q) pos = g + 1;
        }
        int id = pos - 1;
        id = id < 0 ? 0 : (id > NY-2 ? NY-2 : id);
        const float g0 = sy[id] * scale;
        const float g1 = sy[id+1] * scale;
        g_iy[m][j] = id;
        g_fy[m][j] = (q - g0) / (g1 - g0);
        const float gfirst = sy[0] * scale;
        const float glast  = sy[NY-1] * scale;
        g_my[m][j] = (q >= gfirst && q <= glast) ? 1.0f : 0.0f;
    }
}

// One block per (m, t, f). Stage x-interpolated rows into LDS (coalesced
// float4 global reads), then compute the 50x50 points from LDS and
// atomically accumulate w[m]*v into out.
__global__ __launch_bounds__(256) void interp_kernel(
    const float* __restrict__ c1, const float* __restrict__ c2,
    float* __restrict__ out)
{
    const int m = blockIdx.x;
    const int t = blockIdx.y;
    const int f = blockIdx.z;
    const int tid = threadIdx.x;

    // +1 pad column decorrelates the (i,iy) -> bank mapping (NY % 32 == 0).
    __shared__ float xrow[NG][NY + 1];

    const float* __restrict__ preds = (f == 0) ? c1 : c2;
    const int tim = g_ti[t][m];
    const float* __restrict__ slice = preds + (((size_t)m * TS + tim) * NX) * (size_t)NY;

    // ---- stage: x-interp rows, coalesced float4 reads ----
    // NG*NY/4 = 2400 float4 elements
    for (int idx = tid; idx < NG * (NY / 4); idx += blockDim.x) {
        const int i  = idx / (NY / 4);
        const int y4 = (idx - i * (NY / 4)) * 4;
        const int   ixi = g_ix[i];
        const float fxi = g_fx[i];
        const float4 r0 = *(const float4*)(slice + (size_t)ixi * NY + y4);
        const float4 r1 = *(const float4*)(slice + (size_t)(ixi + 1) * NY + y4);
        xrow[i][y4 + 0] = r0.x * (1.0f - fxi) + r1.x * fxi;
        xrow[i][y4 + 1] = r0.y * (1.0f - fxi) + r1.y * fxi;
        xrow[i][y4 + 2] = r0.z * (1.0f - fxi) + r1.z * fxi;
        xrow[i][y4 + 3] = r0.w * (1.0f - fxi) + r1.w * fxi;
    }
    __syncthreads();

    // ---- points: y-interp from LDS, atomic accumulate ----
    const float wm = g_w[m];
    for (int idx = tid; idx < NG * NG; idx += blockDim.x) {
        const int i = idx / NG;
        const int j = idx - i * NG;
        // boundary columns are pre-written with target values; skip them
        if ((f == 0 && j == 0) || (f == 1 && j == NG - 1)) continue;
        const int   iyj = g_iy[m][j];
        const float fyj = g_fy[m][j];
        const float msk = g_mx[i] * g_my[m][j];
        const float v0 = xrow[i][iyj];
        const float v1 = xrow[i][iyj + 1];
        const float v = (v0 * (1.0f - fyj) + v1 * fyj) * msk;
        atomicAdd(&out[(((size_t)f * NTS + t) * NG + i) * NG + j], v * wm);
    }
}

extern "C" void kernel_launch(void* const* d_in, const int* in_sizes, int n_in,
                              void* d_out, int out_size, void* d_ws, size_t ws_size,
                              hipStream_t stream) {
    const float* c1     = (const float*)d_in[0];
    const float* c2     = (const float*)d_in[1];
    const float* params = (const float*)d_in[2];
    const float* src_y  = (const float*)d_in[3];
    const float* stl    = (const float*)d_in[4];
    const float* Wq     = (const float*)d_in[5];
    const float* bq     = (const float*)d_in[6];
    const float* Wk     = (const float*)d_in[7];
    const float* bk     = (const float*)d_in[8];
    const float* lyt    = (const float*)d_in[9];
    const float* ccut   = (const float*)d_in[10];
    const float* cnit   = (const float*)d_in[11];
    float* out = (float*)d_out;

    const int total = 2 * NTS * NG * NG;
    const int init_blocks = (total + 255) / 256;
    prep_init_kernel<<<1 + init_blocks, 256, 0, stream>>>(
        params, src_y, stl, Wq, bq, Wk, bk, lyt, ccut, cnit, out);

    dim3 grid(M, NTS, 2);
    interp_kernel<<<grid, 256, 0, stream>>>(c1, c2, out);
}

// Round 3
// 431.988 us; speedup vs baseline: 1.0112x; 1.0112x over previous
//
#include <hip/hip_runtime.h>
#include <math.h>

#define M   24
#define TS  60
#define NX  192
#define NY  192
#define H_  4
#define D_  8
#define NTS 50   // N_TIME_STEPS
#define NG  50

// Setup results computed by prep each call (always fully rewritten —
// no cross-call state dependence).
__device__ float g_w[M];
__device__ int   g_ti[NTS][M];
__device__ int   g_ix[NG];
__device__ float g_fx[NG];
__device__ float g_mx[NG];
__device__ int   g_iy[M][NG];
__device__ float g_fy[M][NG];
__device__ float g_my[M][NG];

__global__ __launch_bounds__(256) void prep_kernel(
    const float* __restrict__ params, const float* __restrict__ src_y,
    const float* __restrict__ stl,
    const float* __restrict__ Wq, const float* __restrict__ bq,
    const float* __restrict__ Wk, const float* __restrict__ bk,
    const float* __restrict__ lyt_p, const float* __restrict__ ccu_p,
    const float* __restrict__ cni_p)
{
    const int tid = threadIdx.x;
    __shared__ float s_logits[M][H_];
    __shared__ float s_sw[M];

    const float ly_target = lyt_p[0];
    const float c_cu_t = ccu_p[0];
    const float c_ni_t = cni_p[0];

    const float t_ly = (ly_target - 30.0f) / 90.0f;
    const float t_cu = c_cu_t / 0.0029f;
    const float t_ni = c_ni_t / 0.0018f;

    // ---- per-m logits + similarity weight ----
    if (tid < M) {
        const int m = tid;
        const float ly  = params[m*3 + 0];
        const float ccu = params[m*3 + 1];
        const float cni = params[m*3 + 2];
        const float ly_n = (ly - 30.0f) / 90.0f;
        const float cu_n = ccu / 0.0029f;
        const float ni_n = cni / 0.0018f;
        for (int h = 0; h < H_; ++h) {
            float acc = 0.0f;
            for (int d = 0; d < D_; ++d) {
                const int col = h*D_ + d;
                const float q = t_ly*Wq[0*32+col] + t_cu*Wq[1*32+col] + t_ni*Wq[2*32+col] + bq[col];
                const float k = ly_n*Wk[0*32+col] + cu_n*Wk[1*32+col] + ni_n*Wk[2*32+col] + bk[col];
                acc += k * q;
            }
            s_logits[m][h] = acc / sqrtf(8.0f);
        }
        const float dly = ly_n - t_ly, dcu = cu_n - t_cu, dni = ni_n - t_ni;
        const float d2 = (dly*dly + dcu*dcu + dni*dni) / 0.04f;
        s_sw[m] = expf(-d2 * 0.5f);
    }
    __syncthreads();

    if (tid == 0) {
        float attn[M];
        for (int m = 0; m < M; ++m) attn[m] = 0.0f;
        for (int h = 0; h < H_; ++h) {
            float mxv = -1e30f;
            for (int m = 0; m < M; ++m) mxv = fmaxf(mxv, s_logits[m][h]);
            float e[M]; float s = 0.0f;
            for (int m = 0; m < M; ++m) { e[m] = expf(s_logits[m][h] - mxv); s += e[m]; }
            for (int m = 0; m < M; ++m) attn[m] += e[m] / s;
        }
        float ssw = 0.0f;
        for (int m = 0; m < M; ++m) ssw += s_sw[m];
        float w[M]; float wsum = 0.0f;
        for (int m = 0; m < M; ++m) {
            w[m] = (attn[m] * 0.25f) * (s_sw[m] / (ssw + 1e-12f));
            wsum += w[m];
        }
        for (int m = 0; m < M; ++m) g_w[m] = w[m] / (wsum + 1e-12f);
    }

    // ---- ti[t][m] : banker's rounding to match jnp.round ----
    const float step_t = 200.0f / 49.0f;
    for (int idx = tid; idx < NTS*M; idx += blockDim.x) {
        const int t = idx / M, m = idx % M;
        const float tt = (t == NTS-1) ? 200.0f : step_t * (float)t;
        const float r = tt / stl[m] * 59.0f;
        int ti = (int)rintf(r);
        ti = ti < 0 ? 0 : (ti > TS-1 ? TS-1 : ti);
        g_ti[t][m] = ti;
    }

    // ---- x-axis interp setup (grid = linspace(0,100,192), q = linspace(0,100,50)) ----
    if (tid < NG) {
        const int i = tid;
        const float step_x = 100.0f / 191.0f;
        const float step_q = 100.0f / 49.0f;
        const float q = (i == NG-1) ? 100.0f : step_q * (float)i;
        int pos = 0;  // searchsorted(grid, q, 'right')
        for (int g = 0; g < NX; ++g) {
            const float gv = (g == NX-1) ? 100.0f : step_x * (float)g;
            if (gv <= q) pos = g + 1;
        }
        int id = pos - 1;
        id = id < 0 ? 0 : (id > NX-2 ? NX-2 : id);
        const float g0 = (id   == NX-1) ? 100.0f : step_x * (float)id;
        const float g1 = (id+1 == NX-1) ? 100.0f : step_x * (float)(id+1);
        g_ix[i] = id;
        g_fx[i] = (q - g0) / (g1 - g0);
        g_mx[i] = (q >= 0.0f && q <= 100.0f) ? 1.0f : 0.0f;
    }

    // ---- y-axis interp setup per m (grid = src_y[m,:] * (ly_target/lys[m])) ----
    for (int idx = tid; idx < M*NG; idx += blockDim.x) {
        const int m = idx / NG, j = idx % NG;
        const float scale = ly_target / params[m*3 + 0];   // IEEE fp32 div, matches ref
        const float q = (float)j / 49.0f * ly_target;
        const float* sy = src_y + m*NY;
        int pos = 0;
        for (int g = 0; g < NY; ++g) {
            const float gv = sy[g] * scale;                // IEEE fp32 mul, matches ref
            if (gv <= q) pos = g + 1;
        }
        int id = pos - 1;
        id = id < 0 ? 0 : (id > NY-2 ? NY-2 : id);
        const float g0 = sy[id] * scale;
        const float g1 = sy[id+1] * scale;
        g_iy[m][j] = id;
        g_fy[m][j] = (q - g0) / (g1 - g0);
        const float gfirst = sy[0] * scale;
        const float glast  = sy[NY-1] * scale;
        g_my[m][j] = (q >= gfirst && q <= glast) ? 1.0f : 0.0f;
    }
}

// Stage A: one block per (m, t, f). Stage x-interpolated rows into LDS
// (coalesced float4 global reads), compute the 50x50 masked, w[m]-scaled
// values from LDS, and write them coalesced into the partial buffer.
// NO atomics — device-scope atomicAdd resolves at the non-coherent-L2
// coherence point and was suspected ~100s of µs in round 2.
__global__ __launch_bounds__(256) void stage_kernel(
    const float* __restrict__ c1, const float* __restrict__ c2,
    float* __restrict__ partial)
{
    const int m = blockIdx.x;
    const int t = blockIdx.y;
    const int f = blockIdx.z;
    const int tid = threadIdx.x;

    // +4 pad keeps float4 alignment (196 % 4 == 0) while shifting the
    // bank mapping by 4 banks per row (196 % 32 == 4).
    __shared__ float xrow[NG][NY + 4];

    const float* __restrict__ preds = (f == 0) ? c1 : c2;
    const int tim = g_ti[t][m];
    const float* __restrict__ slice = preds + (((size_t)m * TS + tim) * NX) * (size_t)NY;

    // ---- stage: x-interp rows, coalesced float4 reads, float4 LDS stores ----
    for (int idx = tid; idx < NG * (NY / 4); idx += 256) {
        const int i  = idx / (NY / 4);
        const int y4 = (idx - i * (NY / 4)) * 4;
        const int   ixi = g_ix[i];
        const float fxi = g_fx[i];
        const float4 r0 = *(const float4*)(slice + (size_t)ixi * NY + y4);
        const float4 r1 = *(const float4*)(slice + (size_t)(ixi + 1) * NY + y4);
        float4 v;
        v.x = r0.x * (1.0f - fxi) + r1.x * fxi;
        v.y = r0.y * (1.0f - fxi) + r1.y * fxi;
        v.z = r0.z * (1.0f - fxi) + r1.z * fxi;
        v.w = r0.w * (1.0f - fxi) + r1.w * fxi;
        *(float4*)&xrow[i][y4] = v;
    }
    __syncthreads();

    // ---- points: y-interp from LDS, coalesced partial write ----
    const float wm = g_w[m];
    float* __restrict__ dst = partial + (((size_t)f * NTS + t) * M + m) * (size_t)(NG * NG);
    for (int idx = tid; idx < NG * NG; idx += 256) {
        const int i = idx / NG;
        const int j = idx - i * NG;
        const int   iyj = g_iy[m][j];
        const float fyj = g_fy[m][j];
        const float msk = g_mx[i] * g_my[m][j];
        const float v0 = xrow[i][iyj];
        const float v1 = xrow[i][iyj + 1];
        const float v = (v0 * (1.0f - fyj) + v1 * fyj) * msk;
        dst[idx] = v * wm;
    }
}

// Reduce: one thread per output element; sum the 24 m-partials (coalesced:
// consecutive threads read consecutive addresses within each m plane) and
// write final output, overwriting boundary target columns.
__global__ __launch_bounds__(256) void reduce_kernel(
    const float* __restrict__ partial, float* __restrict__ out,
    const float* __restrict__ ccu_p, const float* __restrict__ cni_p)
{
    const int idx = blockIdx.x * 256 + threadIdx.x;
    const int total = 2 * NTS * NG * NG;
    if (idx >= total) return;
    const int p  = idx % (NG * NG);
    const int ft = idx / (NG * NG);       // f*NTS + t
    const int f  = ft / NTS;
    const int j  = p % NG;

    const float* __restrict__ src = partial + (size_t)ft * M * (NG * NG) + p;
    float acc = 0.0f;
    #pragma unroll
    for (int m = 0; m < M; ++m) acc += src[(size_t)m * (NG * NG)];

    if (f == 0 && j == 0)      acc = ccu_p[0];
    if (f == 1 && j == NG - 1) acc = cni_p[0];
    out[idx] = acc;
}

extern "C" void kernel_launch(void* const* d_in, const int* in_sizes, int n_in,
                              void* d_out, int out_size, void* d_ws, size_t ws_size,
                              hipStream_t stream) {
    const float* c1     = (const float*)d_in[0];
    const float* c2     = (const float*)d_in[1];
    const float* params = (const float*)d_in[2];
    const float* src_y  = (const float*)d_in[3];
    const float* stl    = (const float*)d_in[4];
    const float* Wq     = (const float*)d_in[5];
    const float* bq     = (const float*)d_in[6];
    const float* Wk     = (const float*)d_in[7];
    const float* bk     = (const float*)d_in[8];
    const float* lyt    = (const float*)d_in[9];
    const float* ccut   = (const float*)d_in[10];
    const float* cnit   = (const float*)d_in[11];
    float* out     = (float*)d_out;
    float* partial = (float*)d_ws;   // 2*NTS*M*NG*NG floats = 24 MB

    prep_kernel<<<1, 256, 0, stream>>>(params, src_y, stl, Wq, bq, Wk, bk, lyt, ccut, cnit);

    dim3 gridA(M, NTS, 2);
    stage_kernel<<<gridA, 256, 0, stream>>>(c1, c2, partial);

    const int total = 2 * NTS * NG * NG;
    reduce_kernel<<<(total + 255) / 256, 256, 0, stream>>>(partial, out, ccut, cnit);
}

// Round 4
// 417.154 us; speedup vs baseline: 1.0471x; 1.0356x over previous
//
#include <hip/hip_runtime.h>
#include <math.h>

#define M   24
#define TS  60
#define NX  192
#define NY  192
#define H_  4
#define D_  8
#define NTS 50   // N_TIME_STEPS
#define NG  50
#define ITILE 25   // i-rows per stage block (NG/2)

// Setup results computed by prep each call (always fully rewritten —
// no cross-call state dependence).
__device__ float g_w[M];
__device__ int   g_ti[NTS][M];
__device__ int   g_ix[NG];
__device__ float g_fx[NG];
__device__ float g_mx[NG];
__device__ int   g_iy[M][NG];
__device__ float g_fy[M][NG];
__device__ float g_my[M][NG];

__global__ __launch_bounds__(256) void prep_kernel(
    const float* __restrict__ params, const float* __restrict__ src_y,
    const float* __restrict__ stl,
    const float* __restrict__ Wq, const float* __restrict__ bq,
    const float* __restrict__ Wk, const float* __restrict__ bk,
    const float* __restrict__ lyt_p, const float* __restrict__ ccu_p,
    const float* __restrict__ cni_p)
{
    const int tid = threadIdx.x;
    __shared__ float s_logits[M][H_];
    __shared__ float s_sw[M];

    const float ly_target = lyt_p[0];
    const float c_cu_t = ccu_p[0];
    const float c_ni_t = cni_p[0];

    const float t_ly = (ly_target - 30.0f) / 90.0f;
    const float t_cu = c_cu_t / 0.0029f;
    const float t_ni = c_ni_t / 0.0018f;

    // ---- per-m logits + similarity weight ----
    if (tid < M) {
        const int m = tid;
        const float ly  = params[m*3 + 0];
        const float ccu = params[m*3 + 1];
        const float cni = params[m*3 + 2];
        const float ly_n = (ly - 30.0f) / 90.0f;
        const float cu_n = ccu / 0.0029f;
        const float ni_n = cni / 0.0018f;
        for (int h = 0; h < H_; ++h) {
            float acc = 0.0f;
            for (int d = 0; d < D_; ++d) {
                const int col = h*D_ + d;
                const float q = t_ly*Wq[0*32+col] + t_cu*Wq[1*32+col] + t_ni*Wq[2*32+col] + bq[col];
                const float k = ly_n*Wk[0*32+col] + cu_n*Wk[1*32+col] + ni_n*Wk[2*32+col] + bk[col];
                acc += k * q;
            }
            s_logits[m][h] = acc / sqrtf(8.0f);
        }
        const float dly = ly_n - t_ly, dcu = cu_n - t_cu, dni = ni_n - t_ni;
        const float d2 = (dly*dly + dcu*dcu + dni*dni) / 0.04f;
        s_sw[m] = expf(-d2 * 0.5f);
    }
    __syncthreads();

    if (tid == 0) {
        float attn[M];
        for (int m = 0; m < M; ++m) attn[m] = 0.0f;
        for (int h = 0; h < H_; ++h) {
            float mxv = -1e30f;
            for (int m = 0; m < M; ++m) mxv = fmaxf(mxv, s_logits[m][h]);
            float e[M]; float s = 0.0f;
            for (int m = 0; m < M; ++m) { e[m] = expf(s_logits[m][h] - mxv); s += e[m]; }
            for (int m = 0; m < M; ++m) attn[m] += e[m] / s;
        }
        float ssw = 0.0f;
        for (int m = 0; m < M; ++m) ssw += s_sw[m];
        float w[M]; float wsum = 0.0f;
        for (int m = 0; m < M; ++m) {
            w[m] = (attn[m] * 0.25f) * (s_sw[m] / (ssw + 1e-12f));
            wsum += w[m];
        }
        for (int m = 0; m < M; ++m) g_w[m] = w[m] / (wsum + 1e-12f);
    }

    // ---- ti[t][m] : banker's rounding to match jnp.round ----
    const float step_t = 200.0f / 49.0f;
    for (int idx = tid; idx < NTS*M; idx += blockDim.x) {
        const int t = idx / M, m = idx % M;
        const float tt = (t == NTS-1) ? 200.0f : step_t * (float)t;
        const float r = tt / stl[m] * 59.0f;
        int ti = (int)rintf(r);
        ti = ti < 0 ? 0 : (ti > TS-1 ? TS-1 : ti);
        g_ti[t][m] = ti;
    }

    // ---- x-axis interp setup (grid = linspace(0,100,192), q = linspace(0,100,50)) ----
    if (tid < NG) {
        const int i = tid;
        const float step_x = 100.0f / 191.0f;
        const float step_q = 100.0f / 49.0f;
        const float q = (i == NG-1) ? 100.0f : step_q * (float)i;
        int pos = 0;  // searchsorted(grid, q, 'right')
        for (int g = 0; g < NX; ++g) {
            const float gv = (g == NX-1) ? 100.0f : step_x * (float)g;
            if (gv <= q) pos = g + 1;
        }
        int id = pos - 1;
        id = id < 0 ? 0 : (id > NX-2 ? NX-2 : id);
        const float g0 = (id   == NX-1) ? 100.0f : step_x * (float)id;
        const float g1 = (id+1 == NX-1) ? 100.0f : step_x * (float)(id+1);
        g_ix[i] = id;
        g_fx[i] = (q - g0) / (g1 - g0);
        g_mx[i] = (q >= 0.0f && q <= 100.0f) ? 1.0f : 0.0f;
    }

    // ---- y-axis interp setup per m (grid = src_y[m,:] * (ly_target/lys[m])) ----
    // grid is sorted (src_y monotone, scale>0) -> binary search == searchsorted
    // with bit-identical sy[g]*scale comparisons.
    for (int idx = tid; idx < M*NG; idx += blockDim.x) {
        const int m = idx / NG, j = idx % NG;
        const float scale = ly_target / params[m*3 + 0];   // IEEE fp32 div, matches ref
        const float q = (float)j / 49.0f * ly_target;
        const float* sy = src_y + m*NY;
        int lo = 0, hi = NY;                // searchsorted(side='right')
        while (lo < hi) {
            const int mid = (lo + hi) >> 1;
            const float gv = sy[mid] * scale;              // IEEE fp32 mul, matches ref
            if (gv <= q) lo = mid + 1; else hi = mid;
        }
        int id = lo - 1;
        id = id < 0 ? 0 : (id > NY-2 ? NY-2 : id);
        const float g0 = sy[id] * scale;
        const float g1 = sy[id+1] * scale;
        g_iy[m][j] = id;
        g_fy[m][j] = (q - g0) / (g1 - g0);
        const float gfirst = sy[0] * scale;
        const float glast  = sy[NY-1] * scale;
        g_my[m][j] = (q >= gfirst && q <= glast) ? 1.0f : 0.0f;
    }
}

// Stage A: one block per (m, t, f, i-tile). Stage x-interpolated rows for
// ITILE i-values into LDS (coalesced float4 reads), compute the ITILE x NG
// masked, w[m]-scaled values, write coalesced into the partial buffer.
// 19.6 KB LDS -> 8 blocks/CU; 4800 blocks total.
__global__ __launch_bounds__(256) void stage_kernel(
    const float* __restrict__ c1, const float* __restrict__ c2,
    float* __restrict__ partial)
{
    const int m    = blockIdx.x;
    const int t    = blockIdx.y;
    const int fz   = blockIdx.z;
    const int f    = fz >> 1;
    const int i0   = (fz & 1) * ITILE;
    const int tid  = threadIdx.x;

    // +4 pad keeps float4 alignment while shifting bank mapping per row.
    __shared__ float xrow[ITILE][NY + 4];

    const float* __restrict__ preds = (f == 0) ? c1 : c2;
    const int tim = g_ti[t][m];
    const float* __restrict__ slice = preds + (((size_t)m * TS + tim) * NX) * (size_t)NY;

    // ---- stage: x-interp rows, coalesced float4 reads, float4 LDS stores ----
    for (int idx = tid; idx < ITILE * (NY / 4); idx += 256) {
        const int il = idx / (NY / 4);
        const int y4 = (idx - il * (NY / 4)) * 4;
        const int i  = i0 + il;
        const int   ixi = g_ix[i];
        const float fxi = g_fx[i];
        const float4 r0 = *(const float4*)(slice + (size_t)ixi * NY + y4);
        const float4 r1 = *(const float4*)(slice + (size_t)(ixi + 1) * NY + y4);
        float4 v;
        v.x = r0.x * (1.0f - fxi) + r1.x * fxi;
        v.y = r0.y * (1.0f - fxi) + r1.y * fxi;
        v.z = r0.z * (1.0f - fxi) + r1.z * fxi;
        v.w = r0.w * (1.0f - fxi) + r1.w * fxi;
        *(float4*)&xrow[il][y4] = v;
    }
    __syncthreads();

    // ---- points: y-interp from LDS, coalesced partial write ----
    const float wm = g_w[m];
    float* __restrict__ dst = partial + (((size_t)f * NTS + t) * M + m) * (size_t)(NG * NG);
    for (int idx = tid; idx < ITILE * NG; idx += 256) {
        const int il = idx / NG;
        const int j  = idx - il * NG;
        const int i  = i0 + il;
        const int   iyj = g_iy[m][j];
        const float fyj = g_fy[m][j];
        const float msk = g_mx[i] * g_my[m][j];
        const float v0 = xrow[il][iyj];
        const float v1 = xrow[il][iyj + 1];
        const float v = (v0 * (1.0f - fyj) + v1 * fyj) * msk;
        dst[i * NG + j] = v * wm;
    }
}

// Reduce: float4 per thread; sum the 24 m-partials and write final output,
// overwriting boundary target columns.
__global__ __launch_bounds__(256) void reduce_kernel(
    const float* __restrict__ partial, float* __restrict__ out,
    const float* __restrict__ ccu_p, const float* __restrict__ cni_p)
{
    const int q = blockIdx.x * 256 + threadIdx.x;      // float4 index
    const int total4 = (2 * NTS * NG * NG) / 4;        // 125000 -> wait, 250000/4 = 62500
    if (q >= total4) return;
    const int idx = q * 4;                             // first element
    const int p   = idx % (NG * NG);
    const int ft  = idx / (NG * NG);                   // f*NTS + t
    const int f   = ft / NTS;

    const float* __restrict__ src = partial + (size_t)ft * M * (NG * NG) + p;
    float4 acc = make_float4(0.f, 0.f, 0.f, 0.f);
    #pragma unroll
    for (int m = 0; m < M; ++m) {
        const float4 v = *(const float4*)(src + (size_t)m * (NG * NG));
        acc.x += v.x; acc.y += v.y; acc.z += v.z; acc.w += v.w;
    }

    // boundary target columns (NG*NG and 4 share no factor issues: p%NG cycles)
    float vals[4] = {acc.x, acc.y, acc.z, acc.w};
    #pragma unroll
    for (int k = 0; k < 4; ++k) {
        const int j = (p + k) % NG;
        if (f == 0 && j == 0)      vals[k] = ccu_p[0];
        if (f == 1 && j == NG - 1) vals[k] = cni_p[0];
    }
    *(float4*)(out + idx) = make_float4(vals[0], vals[1], vals[2], vals[3]);
}

extern "C" void kernel_launch(void* const* d_in, const int* in_sizes, int n_in,
                              void* d_out, int out_size, void* d_ws, size_t ws_size,
                              hipStream_t stream) {
    const float* c1     = (const float*)d_in[0];
    const float* c2     = (const float*)d_in[1];
    const float* params = (const float*)d_in[2];
    const float* src_y  = (const float*)d_in[3];
    const float* stl    = (const float*)d_in[4];
    const float* Wq     = (const float*)d_in[5];
    const float* bq     = (const float*)d_in[6];
    const float* Wk     = (const float*)d_in[7];
    const float* bk     = (const float*)d_in[8];
    const float* lyt    = (const float*)d_in[9];
    const float* ccut   = (const float*)d_in[10];
    const float* cnit   = (const float*)d_in[11];
    float* out     = (float*)d_out;
    float* partial = (float*)d_ws;   // 2*NTS*M*NG*NG floats = 24 MB

    prep_kernel<<<1, 256, 0, stream>>>(params, src_y, stl, Wq, bq, Wk, bk, lyt, ccut, cnit);

    dim3 gridA(M, NTS, 2 * (NG / ITILE));
    stage_kernel<<<gridA, 256, 0, stream>>>(c1, c2, partial);

    const int total4 = (2 * NTS * NG * NG) / 4;
    reduce_kernel<<<(total4 + 255) / 256, 256, 0, stream>>>(partial, out, ccut, cnit);
}